// Round 10
// baseline (1010.644 us; speedup 1.0000x reference)
//
#include <hip/hip_runtime.h>
#include <hip/hip_bf16.h>

#define NN   13824     // 24^3 neurons
#define BB   256       // batch
#define KDIM 512       // input dim
#define ODIM 1000      // output dim
#define CUBE 24
#define KS   12        // out-gemm split-K (part 12.6MB aliases xp_bf+hA 14.2MB)
#define NQ   3456      // neuron quads (NN/4)

// padded LDS cube layout (1 batch column): x stride 28 (interior x -> x+1),
// 26 y rows, 26 z planes. Row bases are 8B-aligned (728*2 and 28*2 both %8==0).
#define PCX  28
#define PLU  728              // 26*28
#define CUU  18928            // 26*728 ushorts per buffer
#define LDSB2 75712           // 2 buffers * 18928 * 2B

typedef short bf8 __attribute__((ext_vector_type(8)));     // 8 bf16
typedef _Float16 h8 __attribute__((ext_vector_type(8)));   // 8 fp16
typedef _Float16 h2 __attribute__((ext_vector_type(2)));
typedef float f32x4 __attribute__((ext_vector_type(4)));

__device__ __forceinline__ float fast_tanh(float a) {
    float e = __expf(2.0f * a);
    return 1.0f - 2.0f / (e + 1.0f);
}
__device__ __forceinline__ float bf_lo(unsigned u) { return __uint_as_float(u << 16); }
__device__ __forceinline__ float bf_hi(unsigned u) { return __uint_as_float(u & 0xffff0000u); }
__device__ __forceinline__ unsigned short bf_rne(float f) {
    unsigned u = __float_as_uint(f);
    u += 0x7fffu + ((u >> 16) & 1u);
    return (unsigned short)(u >> 16);
}
__device__ __forceinline__ unsigned pk_bf16(float lo, float hi) {
    union { __hip_bfloat162 h; unsigned u; } cv;
    cv.h = __float22bfloat162_rn(make_float2(lo, hi));
    return cv.u;
}
__device__ __forceinline__ bf8 cvt8(float4 a, float4 b) {
    union { bf8 v; unsigned u[4]; } r;
    r.u[0] = pk_bf16(a.x, a.y); r.u[1] = pk_bf16(a.z, a.w);
    r.u[2] = pk_bf16(b.x, b.y); r.u[3] = pk_bf16(b.z, b.w);
    return r.v;
}
// ---- fp16 helpers ----
__device__ __forceinline__ unsigned short f16b(float a) {
    union { _Float16 h; unsigned short s; } c; c.h = (_Float16)a; return c.s;
}
__device__ __forceinline__ h2 u2h(unsigned u) {
    union { unsigned u; h2 h; } c; c.u = u; return c.h;
}
__device__ __forceinline__ float f16lo(unsigned u) { return (float)u2h(u).x; }
__device__ __forceinline__ float f16hi(unsigned u) { return (float)u2h(u).y; }
#if __has_builtin(__builtin_amdgcn_fdot2)
__device__ __forceinline__ float dot2(unsigned w, unsigned v, float acc) {
    return __builtin_amdgcn_fdot2(u2h(w), u2h(v), acc, false);
}
#else
__device__ __forceinline__ float dot2(unsigned w, unsigned v, float acc) {
    h2 W = u2h(w), V = u2h(v);
    return acc + (float)W.x * (float)V.x + (float)W.y * (float)V.y;
}
#endif
__device__ __forceinline__ h8 cvt8f(float4 a, float4 b) {
    union { h8 v; unsigned short s[8]; } r;
    r.s[0] = f16b(a.x); r.s[1] = f16b(a.y); r.s[2] = f16b(a.z); r.s[3] = f16b(a.w);
    r.s[4] = f16b(b.x); r.s[5] = f16b(b.y); r.s[6] = f16b(b.z); r.s[7] = f16b(b.w);
    return r.v;
}

// ---------------------------------------------------------------------------
// x (fp32 [256][512]) -> x_bf (bf16 packed dwords)
// ---------------------------------------------------------------------------
__global__ __launch_bounds__(256) void xbf_kernel(
    const float* __restrict__ x, unsigned* __restrict__ xb)
{
    int i = blockIdx.x * 256 + threadIdx.x;
    float2 v = *(const float2*)&x[(size_t)i * 2];
    xb[i] = pk_bf16(v.x, v.y);
}

// ---------------------------------------------------------------------------
// Weight repack, quad format. Per tap row j (=dz*3+dy), per quad q (4 neurons):
//   wA[j][q] = uint4: (w0,w1) f16-packed for each of the 4 neurons
//   wB[j][q] = uint2: (w2_n0,w2_n1), (w2_n2,w2_n3) f16-packed
// ---------------------------------------------------------------------------
__global__ __launch_bounds__(256) void wprep_kernel(
    const float* __restrict__ wl, uint4* __restrict__ wA, uint2* __restrict__ wB)
{
    int q = blockIdx.x * 256 + threadIdx.x;
    if (q >= NQ) return;
#pragma unroll
    for (int j = 0; j < 9; ++j) {
        unsigned w01[4]; unsigned short w2[4];
#pragma unroll
        for (int i = 0; i < 4; ++i) {
            const int n = q * 4 + i;
            float a = wl[n * 27 + 3 * j + 0];
            float b = wl[n * 27 + 3 * j + 1];
            float c = wl[n * 27 + 3 * j + 2];
            w01[i] = (unsigned)f16b(a) | ((unsigned)f16b(b) << 16);
            w2[i]  = f16b(c);
        }
        uint4 A; A.x = w01[0]; A.y = w01[1]; A.z = w01[2]; A.w = w01[3];
        wA[j * NQ + q] = A;
        uint2 Bv; Bv.x = (unsigned)w2[0] | ((unsigned)w2[1] << 16);
        Bv.y = (unsigned)w2[2] | ((unsigned)w2[3] << 16);
        wB[j * NQ + q] = Bv;
    }
}

// ---------------------------------------------------------------------------
// xproj via MFMA. Writes: xpT f16 [256 cols][NN] (cube path),
// xp_bf bf16 [n][256] + h1 bf16 (fallback path).
// ---------------------------------------------------------------------------
__global__ __launch_bounds__(256) void xproj_mfma(
    const float* __restrict__ w_in, const float* __restrict__ bias,
    const short* __restrict__ xbf, unsigned short* __restrict__ xpT,
    unsigned short* __restrict__ xp_bf, unsigned short* __restrict__ h1)
{
    const int tid = threadIdx.x, w = tid >> 6, lane = tid & 63;
    const int quad = lane >> 4, l16 = lane & 15;
    const int n0 = blockIdx.x * 16;
    const float* __restrict__ arow = &w_in[(size_t)(n0 + l16) * KDIM];

    f32x4 acc[4] = {};

    int ka = quad * 8;
    float4 a0 = *(const float4*)&arow[ka];
    float4 a1 = *(const float4*)&arow[ka + 4];
    bf8 bb[4];
#pragma unroll
    for (int j = 0; j < 4; ++j)
        bb[j] = *(const bf8*)&xbf[(size_t)(w * 64 + j * 16 + l16) * KDIM + ka];

    for (int it = 0; it < 16; ++it) {
        float4 na0{}, na1{}; bf8 nb[4] = {};
        if (it < 15) {
            const int nka = ka + 32;
            na0 = *(const float4*)&arow[nka];
            na1 = *(const float4*)&arow[nka + 4];
#pragma unroll
            for (int j = 0; j < 4; ++j)
                nb[j] = *(const bf8*)&xbf[(size_t)(w * 64 + j * 16 + l16) * KDIM + nka];
        }
        bf8 af = cvt8(a0, a1);
#pragma unroll
        for (int j = 0; j < 4; ++j)
            acc[j] = __builtin_amdgcn_mfma_f32_16x16x32_bf16(af, bb[j], acc[j], 0, 0, 0);
        a0 = na0; a1 = na1;
#pragma unroll
        for (int j = 0; j < 4; ++j) bb[j] = nb[j];
        ka += 32;
    }

#pragma unroll
    for (int j = 0; j < 4; ++j) {
        const int b = w * 64 + j * 16 + l16;
#pragma unroll
        for (int r = 0; r < 4; ++r) {
            const int n = n0 + quad * 4 + r;
            const float v = acc[j][r] + bias[n];
            xp_bf[(size_t)n * BB + b] = bf_rne(v);
            h1[(size_t)n * BB + b]    = bf_rne(fast_tanh(v));
            xpT[(size_t)b * NN + n]   = f16b(v);
        }
    }
}

// ---------------------------------------------------------------------------
// CUBE KERNEL v2: 1 batch column per block (grid 256 = all CUs), whole padded
// cube (f16) in LDS (75.7KB, double-buffered), 29 steps, __syncthreads only.
// Thread = 4 neurons along x: per tap row ONE b64 + ONE b32 LDS read serves
// all 4 outputs (dot2 with alignbit windows + value-masked w2 taps).
// xp lives in registers; weights stream from L2 (746KB/CU/step, 2B/weight floor).
// ---------------------------------------------------------------------------
__global__ __launch_bounds__(512) void cube_kernel(
    const unsigned* __restrict__ xpT32,     // f16[256][NN] as dwords
    const uint4* __restrict__ wA,           // [9][NQ]
    const uint2* __restrict__ wB,           // [9][NQ]
    unsigned short* __restrict__ hT)        // [256][NN] f16 out
{
    extern __shared__ char smem[];
    unsigned*       sdw = (unsigned*)smem;
    unsigned short* sus = (unsigned short*)smem;
    const int tid = threadIdx.x;
    const int c   = blockIdx.x;            // batch column

    // zero both buffers (borders stay zero forever)
    for (int i = tid; i < CUU; i += 512) sdw[i] = 0u;   // CUU dwords = 2 bufs
    __syncthreads();

    // preload xp quads: 7 per thread (NQ=3456 = 6*512 + 384)
    uint2 xq[7];
#pragma unroll
    for (int k = 0; k < 7; ++k) {
        int p = tid + k * 512;
        if (p < NQ) xq[k] = *(const uint2*)&xpT32[(size_t)c * (NN / 2) + 2 * p];
    }

    // init buf0 interior: h1 = tanh(xp)
#pragma unroll
    for (int k = 0; k < 7; ++k) {
        int p = tid + k * 512;
        if (p >= NQ) break;                 // wave-uniform (NQ%64==0)
        int line = p / 6, xqi = p - line * 6;
        int z = line / 24, y = line - z * 24;
        int base = (z + 1) * PLU + (y + 1) * PCX + 4 * xqi + 1;
        sus[base]     = f16b(fast_tanh(f16lo(xq[k].x)));
        sus[base + 1] = f16b(fast_tanh(f16hi(xq[k].x)));
        sus[base + 2] = f16b(fast_tanh(f16lo(xq[k].y)));
        sus[base + 3] = f16b(fast_tanh(f16hi(xq[k].y)));
    }
    __syncthreads();

    int cur = 0;
#pragma unroll 1
    for (int s = 0; s < 29; ++s) {
        const int curB = cur ? CUU : 0;
        const int nxtB = curB ^ CUU;
#pragma unroll
        for (int k = 0; k < 7; ++k) {
            int p = tid + k * 512;
            if (p >= NQ) break;             // wave-uniform
            int line = p / 6, xqi = p - line * 6;
            int z = line / 24, y = line - z * 24;
            // base of (dz=-1,dy=-1) row at padded x = 4*xqi (= interior x0-1)
            const int pb = curB + z * PLU + y * PCX + 4 * xqi;

            float a0 = f16lo(xq[k].x), a1 = f16hi(xq[k].x);
            float a2 = f16lo(xq[k].y), a3 = f16hi(xq[k].y);
#pragma unroll
            for (int j = 0; j < 9; ++j) {
                const int off = (j / 3) * PLU + (j % 3) * PCX;
                uint2 d01 = *(const uint2*)&sus[pb + off];        // v0..v3 (8B aligned)
                unsigned d2 = *(const unsigned*)&sus[pb + off + 4]; // v4,v5
                uint4 wv = wA[(size_t)j * NQ + p];
                uint2 w2 = wB[(size_t)j * NQ + p];
                unsigned s01 = __builtin_amdgcn_alignbit(d01.y, d01.x, 16); // (v1,v2)
                unsigned s12 = __builtin_amdgcn_alignbit(d2, d01.y, 16);    // (v3,v4)
                unsigned mlo1 = d01.y & 0xffffu;       // (v2,0)
                unsigned mhi1 = d01.y & 0xffff0000u;   // (0,v3)
                unsigned mlo2 = d2 & 0xffffu;          // (v4,0)
                unsigned mhi2 = d2 & 0xffff0000u;      // (0,v5)
                a0 = dot2(wv.x, d01.x, a0); a0 = dot2(w2.x, mlo1, a0);
                a1 = dot2(wv.y, s01,  a1);  a1 = dot2(w2.x, mhi1, a1);
                a2 = dot2(wv.z, d01.y, a2); a2 = dot2(w2.y, mlo2, a2);
                a3 = dot2(wv.w, s12,  a3);  a3 = dot2(w2.y, mhi2, a3);
            }
            const int wbase = nxtB + (pb - curB) + PLU + PCX + 1;
            sus[wbase]     = f16b(fast_tanh(a0));
            sus[wbase + 1] = f16b(fast_tanh(a1));
            sus[wbase + 2] = f16b(fast_tanh(a2));
            sus[wbase + 3] = f16b(fast_tanh(a3));
        }
        __syncthreads();
        cur ^= 1;
    }

    // final state -> hT[c][n] (f16), uint2 per quad
    const int fB = cur ? CUU : 0;
#pragma unroll
    for (int k = 0; k < 7; ++k) {
        int p = tid + k * 512;
        if (p >= NQ) break;
        int line = p / 6, xqi = p - line * 6;
        int z = line / 24, y = line - z * 24;
        int base = fB + (z + 1) * PLU + (y + 1) * PCX + 4 * xqi + 1;
        unsigned lo = (unsigned)sus[base]     | ((unsigned)sus[base + 1] << 16);
        unsigned hi = (unsigned)sus[base + 2] | ((unsigned)sus[base + 3] << 16);
        uint2 o; o.x = lo; o.y = hi;
        *(uint2*)&hT[(size_t)c * NN + 4 * p] = o;
    }
}

// ---------------------------------------------------------------------------
// FALLBACK: R5 per-step kernel (bf16, 29 launches) + transpose w/ bf16->f16.
// ---------------------------------------------------------------------------
__device__ __forceinline__ void load_plane_f2(
    const unsigned* __restrict__ h32, int z, int y, int xx, int dof, float2* w9)
{
#pragma unroll
    for (int j = 0; j < 9; ++j) {
        const int dz = j / 3 - 1, dy = j % 3 - 1;
        const int zz = z + dz, yy = y + dy;
        const bool valid = (xx >= 0) & (xx < CUBE) & (zz >= 0) & (zz < CUBE) &
                           (yy >= 0) & (yy < CUBE);
        unsigned v = 0u;
        if (valid) v = h32[(size_t)((zz * 24 + yy) * 24 + xx) * 128 + dof];
        w9[j] = make_float2(bf_lo(v), bf_hi(v));
    }
}

__global__ __launch_bounds__(128) void step_kernel(
    const unsigned* __restrict__ hprev, const unsigned* __restrict__ xp,
    const float* __restrict__ wl, unsigned* __restrict__ hnext)
{
    const int tid  = threadIdx.x;
    const int wv   = __builtin_amdgcn_readfirstlane(tid >> 6);
    const int lane = tid & 63;
    const int bid   = blockIdx.x;
    const int zhi   = bid & 7;
    const int inner = bid >> 3;
    const int y     = inner % 24;
    const int r     = inner / 24;
    const int xc    = r & 3;
    const int zlo   = r >> 2;
    const int z     = zhi * 3 + zlo;
    const int x0    = xc * 6;
    const int dof   = wv * 64 + lane;

    float2 win[5][9];
    load_plane_f2(hprev, z, y, x0 - 1, dof, win[0]);
    load_plane_f2(hprev, z, y, x0,     dof, win[1]);
    load_plane_f2(hprev, z, y, x0 + 1, dof, win[2]);
    load_plane_f2(hprev, z, y, x0 + 2, dof, win[3]);

#pragma unroll
    for (int xi = 0; xi < 6; ++xi) {
        const int x = x0 + xi;
        if (xi <= 3) load_plane_f2(hprev, z, y, x + 3, dof, win[(xi + 4) % 5]);
        const int n = (z * 24 + y) * 24 + x;
        const float* __restrict__ wn = &wl[(size_t)n * 27];
        const unsigned xpv = xp[(size_t)n * 128 + dof];
        float2 acc = make_float2(bf_lo(xpv), bf_hi(xpv));
        const float2* pm = win[xi % 5];
        const float2* pc = win[(xi + 1) % 5];
        const float2* pp = win[(xi + 2) % 5];
#pragma unroll
        for (int j = 0; j < 9; ++j) {
            const float w0 = wn[3 * j], w1 = wn[3 * j + 1], w2 = wn[3 * j + 2];
            acc.x += w0 * pm[j].x + w1 * pc[j].x + w2 * pp[j].x;
            acc.y += w0 * pm[j].y + w1 * pc[j].y + w2 * pp[j].y;
        }
        hnext[(size_t)n * 128 + dof] = pk_bf16(fast_tanh(acc.x), fast_tanh(acc.y));
    }
}

__global__ __launch_bounds__(256) void transpose_cvt(
    const unsigned* __restrict__ h32, unsigned* __restrict__ hT32)
{
    __shared__ unsigned short T[64][66];
    const int tid = threadIdx.x;
    const int rr = tid >> 2, g = tid & 3;
    const int k0 = blockIdx.x * 64, b0 = blockIdx.y * 64;
#pragma unroll
    for (int i = 0; i < 8; ++i) {
        unsigned d = h32[(size_t)(k0 + rr) * 128 + b0 / 2 + g * 8 + i];
        const int bl = (g * 8 + i) * 2;
        T[bl][rr]     = (unsigned short)(d & 0xffffu);
        T[bl + 1][rr] = (unsigned short)(d >> 16);
    }
    __syncthreads();
#pragma unroll
    for (int i = 0; i < 8; ++i) {
        const int kl = (g * 8 + i) * 2;
        float fa = __uint_as_float((unsigned)T[rr][kl] << 16);
        float fb = __uint_as_float((unsigned)T[rr][kl + 1] << 16);
        hT32[(size_t)(b0 + rr) * (NN / 2) + k0 / 2 + g * 8 + i] =
            (unsigned)f16b(fa) | ((unsigned)f16b(fb) << 16);
    }
}

// ---------------------------------------------------------------------------
// Output GEMM via f16 MFMA, split-K=12, software-pipelined.
// ---------------------------------------------------------------------------
__global__ __launch_bounds__(256) void outgemm_mfma(
    const float* __restrict__ wout, const _Float16* __restrict__ hT,
    float* __restrict__ part)
{
    const int tid = threadIdx.x, w = tid >> 6, lane = tid & 63;
    const int quad = lane >> 4, l16 = lane & 15;
    const int o0 = blockIdx.x * 32;
    const int kb = blockIdx.y * (NN / KS);
    const int b0 = w * 64;

    const int oa = o0 + l16, ob = o0 + 16 + l16;
    const bool av0 = oa < ODIM, av1 = ob < ODIM;
    const float* __restrict__ ar0 = &wout[(size_t)oa * NN];
    const float* __restrict__ ar1 = &wout[(size_t)ob * NN];
    const float4 z4 = {0.f, 0.f, 0.f, 0.f};

    f32x4 acc[2][4] = {};

    int ka = kb + quad * 8;
    float4 a00 = av0 ? *(const float4*)&ar0[ka]     : z4;
    float4 a01 = av0 ? *(const float4*)&ar0[ka + 4] : z4;
    float4 a10 = av1 ? *(const float4*)&ar1[ka]     : z4;
    float4 a11 = av1 ? *(const float4*)&ar1[ka + 4] : z4;
    h8 bb[4];
#pragma unroll
    for (int j = 0; j < 4; ++j)
        bb[j] = *(const h8*)&hT[(size_t)(b0 + j * 16 + l16) * NN + ka];

    const int ITER = (NN / KS) / 32;    // 36
    for (int it = 0; it < ITER; ++it) {
        float4 na00{}, na01{}, na10{}, na11{}; h8 nb[4] = {};
        if (it < ITER - 1) {
            const int nka = ka + 32;
            na00 = av0 ? *(const float4*)&ar0[nka]     : z4;
            na01 = av0 ? *(const float4*)&ar0[nka + 4] : z4;
            na10 = av1 ? *(const float4*)&ar1[nka]     : z4;
            na11 = av1 ? *(const float4*)&ar1[nka + 4] : z4;
#pragma unroll
            for (int j = 0; j < 4; ++j)
                nb[j] = *(const h8*)&hT[(size_t)(b0 + j * 16 + l16) * NN + nka];
        }
        h8 af0 = cvt8f(a00, a01);
        h8 af1 = cvt8f(a10, a11);
#pragma unroll
        for (int j = 0; j < 4; ++j) {
            acc[0][j] = __builtin_amdgcn_mfma_f32_16x16x32_f16(af0, bb[j], acc[0][j], 0, 0, 0);
            acc[1][j] = __builtin_amdgcn_mfma_f32_16x16x32_f16(af1, bb[j], acc[1][j], 0, 0, 0);
        }
        a00 = na00; a01 = na01; a10 = na10; a11 = na11;
#pragma unroll
        for (int j = 0; j < 4; ++j) bb[j] = nb[j];
        ka += 32;
    }

#pragma unroll
    for (int i = 0; i < 2; ++i)
#pragma unroll
        for (int j = 0; j < 4; ++j) {
            const int b = b0 + j * 16 + l16;
#pragma unroll
            for (int r = 0; r < 4; ++r) {
                const int o = o0 + i * 16 + quad * 4 + r;
                part[((size_t)blockIdx.y * 1024 + o) * BB + b] = acc[i][j][r];
            }
        }
}

__global__ __launch_bounds__(256) void reduce_kernel(
    const float* __restrict__ part, const float* __restrict__ bias,
    float* __restrict__ out)
{
    const int o = blockIdx.x, b = threadIdx.x;
    float s = bias[o];
#pragma unroll
    for (int kc = 0; kc < KS; ++kc)
        s += part[((size_t)kc * 1024 + o) * BB + b];
    out[(size_t)b * ODIM + o] = s;
}

extern "C" void kernel_launch(void* const* d_in, const int* in_sizes, int n_in,
                              void* d_out, int out_size, void* d_ws, size_t ws_size,
                              hipStream_t stream)
{
    const float* x       = (const float*)d_in[0];
    const float* w_in    = (const float*)d_in[1];
    const float* b_in    = (const float*)d_in[2];
    const float* w_local = (const float*)d_in[3];
    const float* w_out   = (const float*)d_in[4];
    const float* b_out   = (const float*)d_in[5];
    float* out = (float*)d_out;

    char* p = (char*)d_ws;
    unsigned short* xpT   = (unsigned short*)p;  p += (size_t)256 * NN * 2;   // 7.08 MB
    unsigned short* hT    = (unsigned short*)p;  p += (size_t)256 * NN * 2;   // 7.08 MB
    unsigned short* x_bf  = (unsigned short*)p;  p += (size_t)BB * KDIM * 2;  // 0.26 MB
    uint4*          wA    = (uint4*)p;           p += (size_t)9 * NQ * 16;    // 0.50 MB
    uint2*          wB    = (uint2*)p;           p += (size_t)9 * NQ * 8;     // 0.25 MB
    unsigned short* xp_bf = (unsigned short*)p;  p += (size_t)NN * BB * 2;    // 7.08 MB
    unsigned short* hA    = (unsigned short*)p;  p += (size_t)NN * BB * 2;    // 7.08 MB
    unsigned short* hB    = (unsigned short*)p;  p += (size_t)NN * BB * 2;    // 7.08 MB
    float* part = (float*)xp_bf;   // 12*1024*256*4 = 12.6 MB <= xp_bf+hA (14.2 MB)

    xbf_kernel<<<256, 256, 0, stream>>>(x, (unsigned*)x_bf);
    wprep_kernel<<<14, 256, 0, stream>>>(w_local, wA, wB);
    xproj_mfma<<<864, 256, 0, stream>>>(w_in, b_in, (const short*)x_bf,
                                        xpT, xp_bf, hA);

    bool fast = hipFuncSetAttribute((const void*)cube_kernel,
        hipFuncAttributeMaxDynamicSharedMemorySize, LDSB2) == hipSuccess;

    if (fast) {
        cube_kernel<<<256, 512, LDSB2, stream>>>((const unsigned*)xpT, wA, wB, hT);
    } else {
        const unsigned* hp = (const unsigned*)hA;
        unsigned* hn = (unsigned*)hB;
        for (int s = 0; s < 29; ++s) {     // 29 odd -> final in hB
            step_kernel<<<2304, 128, 0, stream>>>(hp, (const unsigned*)xp_bf, w_local, hn);
            unsigned* t = (unsigned*)hp; hp = hn; hn = t;
        }
        transpose_cvt<<<dim3(216, 4), 256, 0, stream>>>((const unsigned*)hB, (unsigned*)hT);
    }

    outgemm_mfma<<<dim3(32, KS), 256, 0, stream>>>(w_out, (const _Float16*)hT, part);
    reduce_kernel<<<ODIM, 256, 0, stream>>>(part, b_out, out);
}